// Round 12
// baseline (561.136 us; speedup 1.0000x reference)
//
#include <hip/hip_runtime.h>
#include <math.h>

#define FDIM 512
#define HIDDIM 256
#define HB 128   // edge-chunk blocks for hist/fill
#define SCH 1024 // elements per scan-part block
#define LDSK 32  // K-shorts per LDS row (no pad: required by global_load_lds layout)

typedef __bf16 bf16x8 __attribute__((ext_vector_type(8)));
typedef __bf16 bf16x4 __attribute__((ext_vector_type(4)));
typedef float floatx4 __attribute__((ext_vector_type(4)));

__device__ __forceinline__ float lrelu(float x, float s) { return x >= 0.0f ? x : s * x; }

__device__ __forceinline__ float bf2f(unsigned int u) {
  union { float f; unsigned int i; } v; v.i = u << 16; return v.f;
}
__device__ __forceinline__ unsigned short f2bf(float f) {
  union { float f; unsigned int u; } v; v.f = f;
  unsigned int x = v.u;
  return (unsigned short)((x + 0x7fffu + ((x >> 16) & 1u)) >> 16);
}

__device__ __forceinline__ void async_copy16(const unsigned short* g, unsigned short* l) {
  __builtin_amdgcn_global_load_lds((const __attribute__((address_space(1))) unsigned int*)g,
                                   (__attribute__((address_space(3))) unsigned int*)l, 16, 0, 0);
}

__device__ __forceinline__ float waveReduceSum(float v) {
#pragma unroll
  for (int o = 32; o; o >>= 1) v += __shfl_down(v, o, 64);
  return v;
}

__device__ __forceinline__ float blockReduceSum256(float v) {
  __shared__ float sm[4];
  int lane = threadIdx.x & 63, w = threadIdx.x >> 6;
  v = waveReduceSum(v);
  __syncthreads();
  if (lane == 0) sm[w] = v;
  __syncthreads();
  return sm[0] + sm[1] + sm[2] + sm[3];
}

__device__ __forceinline__ float blockReduceMax256(float v) {
  __shared__ float sm[4];
  int lane = threadIdx.x & 63, w = threadIdx.x >> 6;
#pragma unroll
  for (int o = 32; o; o >>= 1) v = fmaxf(v, __shfl_down(v, o, 64));
  __syncthreads();
  if (lane == 0) sm[w] = v;
  __syncthreads();
  return fmaxf(fmaxf(sm[0], sm[1]), fmaxf(sm[2], sm[3]));
}

// ---------------- CSR build ----------------
__global__ __launch_bounds__(256) void k_hist2(const int* __restrict__ row, const int* __restrict__ col,
                                               int* __restrict__ cnt_r, int* __restrict__ cnt_c,
                                               int E, int nchunk) {
  __shared__ int h[2048];
  int b = blockIdx.x, t = threadIdx.x;
  for (int i = t; i < 2048; i += 256) h[i] = 0;
  __syncthreads();
  int s = b * nchunk, e = min(E, s + nchunk);
  for (int j = s + t; j < e; j += 256) {
    atomicAdd(&h[col[j]], 1);
    atomicAdd(&cnt_r[row[j]], 1);
  }
  __syncthreads();
  for (int i = t; i < 2048; i += 256) {
    int v = h[i];
    if (v) atomicAdd(&cnt_c[i], v);
  }
}

__global__ __launch_bounds__(256) void k_scan_part(const int* __restrict__ cnt, int* __restrict__ off,
                                                   int* __restrict__ btot, int n) {
  int b = blockIdx.x, t = threadIdx.x;
  int base = b * SCH + t * 4;
  int v[4];
#pragma unroll
  for (int i = 0; i < 4; ++i) v[i] = (base + i < n) ? cnt[base + i] : 0;
  int s = v[0] + v[1] + v[2] + v[3];
  int lane = t & 63, w = t >> 6;
  int x = s;
#pragma unroll
  for (int o = 1; o < 64; o <<= 1) {
    int y = __shfl_up(x, o, 64);
    if (lane >= o) x += y;
  }
  __shared__ int ws[4];
  if (lane == 63) ws[w] = x;
  __syncthreads();
  int wpre = 0;
  for (int i = 0; i < w; ++i) wpre += ws[i];
  int run = wpre + x - s;
#pragma unroll
  for (int i = 0; i < 4; ++i) {
    if (base + i < n) off[base + i] = run;
    run += v[i];
  }
  if (t == 255) btot[b] = wpre + x;
}

// block 0: exclusive-scan btot (row mid-scan). block 1: 2048-col scan -> off_c, gcur.
__global__ __launch_bounds__(256) void k_scan_midcol(int* __restrict__ btot, int nb,
                                                     const int* __restrict__ cnt_c, int* __restrict__ off_c,
                                                     int* __restrict__ gcur) {
  int t = threadIdx.x, lane = t & 63, w = t >> 6;
  __shared__ int ws[4];
  if (blockIdx.x == 0) {
    int v = (t < nb) ? btot[t] : 0;
    int x = v;
#pragma unroll
    for (int o = 1; o < 64; o <<= 1) {
      int y = __shfl_up(x, o, 64);
      if (lane >= o) x += y;
    }
    if (lane == 63) ws[w] = x;
    __syncthreads();
    int wpre = 0;
    for (int i = 0; i < w; ++i) wpre += ws[i];
    if (t < nb) btot[t] = wpre + x - v;
    if (t == 255) btot[nb] = wpre + x;
  } else {
    int base = t * 8;
    int v[8];
#pragma unroll
    for (int i = 0; i < 8; ++i) v[i] = cnt_c[base + i];
    int s = 0;
#pragma unroll
    for (int i = 0; i < 8; ++i) s += v[i];
    int x = s;
#pragma unroll
    for (int o = 1; o < 64; o <<= 1) {
      int y = __shfl_up(x, o, 64);
      if (lane >= o) x += y;
    }
    if (lane == 63) ws[w] = x;
    __syncthreads();
    int wpre = 0;
    for (int i = 0; i < w; ++i) wpre += ws[i];
    int run = wpre + x - s;
#pragma unroll
    for (int i = 0; i < 8; ++i) {
      off_c[base + i] = run;
      gcur[base + i] = run;
      run += v[i];
    }
    if (t == 255) off_c[2048] = wpre + x;
  }
}

__global__ __launch_bounds__(256) void k_scan_add(int* __restrict__ off, const int* __restrict__ btot,
                                                  int n, int nb) {
  int b = blockIdx.x, t = threadIdx.x;
  int base = b * SCH + t * 4;
  int add = btot[b];
#pragma unroll
  for (int i = 0; i < 4; ++i)
    if (base + i < n) off[base + i] += add;
  if (b == 0 && t == 0) off[n] = btot[nb];
}

// fill: col side via LDS cursors + bulk reservation; writes rj and prj, cj for prop_row.
__global__ __launch_bounds__(256) void k_fill3(const int* __restrict__ row, const int* __restrict__ col,
                                               int* __restrict__ gcur, const int* __restrict__ off_r,
                                               int* __restrict__ cur_r, int* __restrict__ prj,
                                               int* __restrict__ rj, int* __restrict__ cj,
                                               int E, int nchunk) {
  __shared__ int h[2048];
  __shared__ int lbase[2048];
  int b = blockIdx.x, t = threadIdx.x;
  for (int i = t; i < 2048; i += 256) h[i] = 0;
  __syncthreads();
  int s = b * nchunk, e = min(E, s + nchunk);
  for (int j = s + t; j < e; j += 256) atomicAdd(&h[col[j]], 1);
  __syncthreads();
  for (int i = t; i < 2048; i += 256) {
    int c = h[i];
    lbase[i] = c ? atomicAdd(&gcur[i], c) : 0;
    h[i] = 0;
  }
  __syncthreads();
  for (int j = s + t; j < e; j += 256) {
    int r = row[j], c = col[j];
    int slot_c = lbase[c] + atomicAdd(&h[c], 1);
    int slot_r = off_r[r] + atomicAdd(&cur_r[r], 1);
    rj[slot_c] = r;
    prj[slot_c] = slot_r;
    cj[slot_r] = c;
  }
}

// ---------------- conversions ----------------
__global__ __launch_bounds__(256) void k_hi(const float* __restrict__ A, unsigned short* __restrict__ hi, int n4) {
  int i = blockIdx.x * 256 + threadIdx.x;
  if (i < n4) {
    float4 v = ((const float4*)A)[i];
    ushort4 h;
    h.x = f2bf(v.x); h.y = f2bf(v.y); h.z = f2bf(v.z); h.w = f2bf(v.w);
    ((ushort4*)hi)[i] = h;
  }
}

__global__ __launch_bounds__(256) void k_prep_w_hi2(const float* __restrict__ W1, unsigned short* __restrict__ t1,
                                                    const float* __restrict__ W2, unsigned short* __restrict__ t2,
                                                    int K, int Nc) {
  const float* W = blockIdx.z ? W2 : W1;
  unsigned short* th = blockIdx.z ? t2 : t1;
  int n = blockIdx.x * 16 + (threadIdx.x & 15);
  int k = blockIdx.y * 16 + (threadIdx.x >> 4);
  th[(size_t)n * K + k] = f2bf(W[(size_t)k * Nc + n]);
}

__global__ __launch_bounds__(256) void k_prep_w2(const float* __restrict__ Wa, unsigned short* __restrict__ tha,
                                                 unsigned short* __restrict__ tla, const float* __restrict__ Wb,
                                                 unsigned short* __restrict__ thb, unsigned short* __restrict__ tlb,
                                                 int K, int Nc) {
  const float* W = blockIdx.z ? Wb : Wa;
  unsigned short* th = blockIdx.z ? thb : tha;
  unsigned short* tl = blockIdx.z ? tlb : tla;
  int n = blockIdx.x * 16 + (threadIdx.x & 15);
  int k = blockIdx.y * 16 + (threadIdx.x >> 4);
  float v = W[(size_t)k * Nc + n];
  unsigned short h = f2bf(v);
  unsigned short l = f2bf(v - bf2f(h));
  th[(size_t)n * K + k] = h;
  tl[(size_t)n * K + k] = l;
}

// ---------------- attention matvecs ----------------
__global__ __launch_bounds__(256) void k_wv2(const float* __restrict__ W1, const float* __restrict__ a1,
                                             const float* __restrict__ W2, const float* __restrict__ a2,
                                             float* __restrict__ wv1, float* __restrict__ wv2) {
  int lane = threadIdx.x & 63, w = threadIdx.x >> 6;
  int k = blockIdx.x * 4 + w;
  const float* W = blockIdx.y ? W2 : W1;
  const float* a = blockIdx.y ? a2 : a1;
  float* wv = blockIdx.y ? wv2 : wv1;
  float s = 0.f;
  for (int f = lane; f < FDIM; f += 64) s = fmaf(W[(size_t)k * FDIM + f], a[f], s);
  s = waveReduceSum(s);
  if (lane == 0) wv[k] = s;
}

__global__ __launch_bounds__(256) void k_ea2(const float* __restrict__ X, const float* __restrict__ wv1,
                                             const float* __restrict__ wv2, float* __restrict__ ea1,
                                             float* __restrict__ ea2, int Mr) {
  int lane = threadIdx.x & 63, w = threadIdx.x >> 6;
  int m = blockIdx.x * 4 + w;
  if (m < Mr) {
    float s1 = 0.f, s2 = 0.f;
    for (int f = lane; f < FDIM; f += 64) {
      float v = X[(size_t)m * FDIM + f];
      s1 = fmaf(v, wv1[f], s1);
      s2 = fmaf(v, wv2[f], s2);
    }
    s1 = waveReduceSum(s1);
    s2 = waveReduceSum(s2);
    if (lane == 0) { ea1[m] = s1; ea2[m] = s2; }
  }
}

// XCD-aware decode for GEMMs: panel = (id>>5)*8 + (id&7), c = (id>>3)&3.
__device__ __forceinline__ bool xcd_decode(int id, int nP, int& panel, int& c) {
  panel = ((id >> 5) << 3) + (id & 7);
  c = (id >> 3) & 3;
  return panel < nP;
}

// ---------------- conv GEMM: plain bf16, async staging, fused att-rowdot ----------------
__global__ __launch_bounds__(256, 1) void gemm_conv(const unsigned short* __restrict__ Ah,
                                                    const unsigned short* __restrict__ Bth,
                                                    unsigned short* __restrict__ Cb,
                                                    const float* __restrict__ att, float* __restrict__ xa,
                                                    int Mr, int K, int Nc, int nP) {
  int panel, cblk;
  if (!xcd_decode(blockIdx.x, nP, panel, cblk)) return;
  __shared__ unsigned short lds[2 * 128 * LDSK];
  int tid = threadIdx.x, lane = tid & 63, w = tid >> 6;
  int wr = w >> 1, wc = w & 1;
  int rowB = panel * 128, colB = cblk * 128;

  const unsigned short* src = (w < 2) ? Ah : Bth;
  int baseRow = ((w < 2) ? rowB : colB) + 64 * (w & 1);
  int maxRow = (w < 2) ? (Mr - 1) : (Nc - 1);
  int slr = lane >> 2, slc = lane & 3;
  unsigned short* dstBase = &lds[((w >> 1) * 128 + (w & 1) * 64) * LDSK];

  size_t gro[4];
#pragma unroll
  for (int seg = 0; seg < 4; ++seg) {
    int rg = baseRow + seg * 16 + slr;
    if (rg > maxRow) rg = maxRow;
    gro[seg] = (size_t)rg * K + slc * 8;
  }

  floatx4 zero4 = {0.f, 0.f, 0.f, 0.f};
  floatx4 acc[4][4];
#pragma unroll
  for (int i = 0; i < 4; ++i)
#pragma unroll
    for (int j = 0; j < 4; ++j) acc[i][j] = zero4;

  int fr = lane & 15, fq = lane >> 4;
  int offA = (wr * 64 + fr) * LDSK + fq * 8;
  int offB = 128 * LDSK + (wc * 64 + fr) * LDSK + fq * 8;

  for (int k0 = 0; k0 < K; k0 += 32) {
#pragma unroll
    for (int seg = 0; seg < 4; ++seg) async_copy16(src + gro[seg] + k0, dstBase + seg * 16 * LDSK);
    __syncthreads();
    bf16x8 a[4], b[4];
#pragma unroll
    for (int t = 0; t < 4; ++t) {
      a[t] = *(const bf16x8*)(&lds[offA + t * 16 * LDSK]);
      b[t] = *(const bf16x8*)(&lds[offB + t * 16 * LDSK]);
    }
#pragma unroll
    for (int ti = 0; ti < 4; ++ti)
#pragma unroll
      for (int tj = 0; tj < 4; ++tj)
        acc[ti][tj] = __builtin_amdgcn_mfma_f32_16x16x32_bf16(a[ti], b[tj], acc[ti][tj], 0, 0, 0);
    __syncthreads();
  }

  int colL = colB + wc * 64 + fr;
  int rowL = rowB + wr * 64 + fq * 4;
  float attv[4];
#pragma unroll
  for (int tj = 0; tj < 4; ++tj) attv[tj] = att[colL + tj * 16];
#pragma unroll
  for (int ti = 0; ti < 4; ++ti) {
#pragma unroll
    for (int r = 0; r < 4; ++r) {
      int rr = rowL + ti * 16 + r;
      if (rr < Mr) {
        float dot = 0.f;
#pragma unroll
        for (int tj = 0; tj < 4; ++tj) {
          float v = acc[ti][tj][r];
          Cb[(size_t)rr * Nc + colL + tj * 16] = f2bf(v);
          dot = fmaf(v, attv[tj], dot);
        }
#pragma unroll
        for (int o = 1; o < 16; o <<= 1) dot += __shfl_xor(dot, o, 64);
        if ((lane & 15) == 0) atomicAdd(&xa[rr], dot);
      }
    }
  }
}

// ---------------- fused FC1+FC2+classifier (XCD-swizzled) ----------------
__global__ __launch_bounds__(256, 1) void gemm_fc_cls(const unsigned short* __restrict__ A1,
                                                      const unsigned short* __restrict__ B1h,
                                                      const unsigned short* __restrict__ B1l,
                                                      const float* __restrict__ b1,
                                                      const unsigned short* __restrict__ A2,
                                                      const unsigned short* __restrict__ B2h,
                                                      const unsigned short* __restrict__ B2l,
                                                      const float* __restrict__ b2,
                                                      const float* __restrict__ clsW, const float* __restrict__ clsb,
                                                      float* __restrict__ logits, int Mr, int K, int nP) {
  int panel, cblk;
  if (!xcd_decode(blockIdx.x, nP, panel, cblk)) return;
  __shared__ unsigned short lds[(128 + 2 * 64) * LDSK];
  int tid = threadIdx.x, lane = tid & 63, w = tid >> 6;
  int wr = w >> 1, wc = w & 1;
  int rowB = panel * 128, colB = cblk * 64;

  int slr = lane >> 2, slc = lane & 3;
  int baseRow = (w < 2) ? (rowB + 64 * w) : colB;
  int maxRow = (w < 2) ? (Mr - 1) : (HIDDIM - 1);
  unsigned short* dstBase = &lds[w * 64 * LDSK];

  size_t gro[4];
#pragma unroll
  for (int seg = 0; seg < 4; ++seg) {
    int rg = baseRow + seg * 16 + slr;
    if (rg > maxRow) rg = maxRow;
    gro[seg] = (size_t)rg * K + slc * 8;
  }

  int fr = lane & 15, fq = lane >> 4;
  int offA = (wr * 64 + fr) * LDSK + fq * 8;
  int offBh = (128 + wc * 32 + fr) * LDSK + fq * 8;
  int offBl = offBh + 64 * LDSK;

  floatx4 zero4 = {0.f, 0.f, 0.f, 0.f};
  floatx4 acc1[4][2], acc2[4][2];
#pragma unroll
  for (int i = 0; i < 4; ++i) {
    acc1[i][0] = zero4; acc1[i][1] = zero4;
    acc2[i][0] = zero4; acc2[i][1] = zero4;
  }

#pragma unroll
  for (int L = 0; L < 2; ++L) {
    const unsigned short* src =
        (L == 0) ? ((w < 2) ? A1 : (w == 2) ? B1h : B1l)
                 : ((w < 2) ? A2 : (w == 2) ? B2h : B2l);
    for (int k0 = 0; k0 < K; k0 += 32) {
#pragma unroll
      for (int seg = 0; seg < 4; ++seg) async_copy16(src + gro[seg] + k0, dstBase + seg * 16 * LDSK);
      __syncthreads();
      bf16x8 a[4], bh[2], bl[2];
#pragma unroll
      for (int t = 0; t < 4; ++t) a[t] = *(const bf16x8*)(&lds[offA + t * 16 * LDSK]);
#pragma unroll
      for (int t = 0; t < 2; ++t) {
        bh[t] = *(const bf16x8*)(&lds[offBh + t * 16 * LDSK]);
        bl[t] = *(const bf16x8*)(&lds[offBl + t * 16 * LDSK]);
      }
      if (L == 0) {
#pragma unroll
        for (int ti = 0; ti < 4; ++ti)
#pragma unroll
          for (int tj = 0; tj < 2; ++tj) {
            acc1[ti][tj] = __builtin_amdgcn_mfma_f32_16x16x32_bf16(a[ti], bh[tj], acc1[ti][tj], 0, 0, 0);
            acc1[ti][tj] = __builtin_amdgcn_mfma_f32_16x16x32_bf16(a[ti], bl[tj], acc1[ti][tj], 0, 0, 0);
          }
      } else {
#pragma unroll
        for (int ti = 0; ti < 4; ++ti)
#pragma unroll
          for (int tj = 0; tj < 2; ++tj) {
            acc2[ti][tj] = __builtin_amdgcn_mfma_f32_16x16x32_bf16(a[ti], bh[tj], acc2[ti][tj], 0, 0, 0);
            acc2[ti][tj] = __builtin_amdgcn_mfma_f32_16x16x32_bf16(a[ti], bl[tj], acc2[ti][tj], 0, 0, 0);
          }
      }
      __syncthreads();
    }
  }

  int colL = colB + wc * 32 + fr;
  int rowL = rowB + wr * 64 + fq * 4;
  float cw0[2], cw1[2], bb1[2], bb2[2];
#pragma unroll
  for (int tj = 0; tj < 2; ++tj) {
    int c = colL + tj * 16;
    cw0[tj] = clsW[2 * c];
    cw1[tj] = clsW[2 * c + 1];
    bb1[tj] = b1[c];
    bb2[tj] = b2[c];
  }
  bool addBias = (cblk == 0 && wc == 0);
  float cb0 = clsb[0], cb1 = clsb[1];
#pragma unroll
  for (int ti = 0; ti < 4; ++ti) {
#pragma unroll
    for (int r = 0; r < 4; ++r) {
      int rr = rowL + ti * 16 + r;
      if (rr < Mr) {
        float d0 = 0.f, d1 = 0.f;
#pragma unroll
        for (int tj = 0; tj < 2; ++tj) {
          float v = lrelu(acc1[ti][tj][r] + bb1[tj], 0.01f) + lrelu(acc2[ti][tj][r] + bb2[tj], 0.01f);
          d0 = fmaf(v, cw0[tj], d0);
          d1 = fmaf(v, cw1[tj], d1);
        }
#pragma unroll
        for (int o = 1; o < 16; o <<= 1) {
          d0 += __shfl_xor(d0, o, 64);
          d1 += __shfl_xor(d1, o, 64);
        }
        if ((lane & 15) == 0) {
          if (addBias) { d0 += cb0; d1 += cb1; }
          atomicAdd(&logits[2 * (size_t)rr], d0);
          atomicAdd(&logits[2 * (size_t)rr + 1], d1);
        }
      }
    }
  }
}

// ---------------- fused softmax + propagate (nodes -> hyperedges), feature-half split ----
// Grid 2*M (M mult of 4): x=id&7, half=x>>2, m=(id>>3)*4+(x&3). XCDs 0-3 do feat half 0,
// XCDs 4-7 do half 1 -> per-XCD xl working set halves (10.25 MB).
__global__ __launch_bounds__(256) void k_prop_col_f(const unsigned short* __restrict__ xl,
                                                    const float* __restrict__ xa, const float* __restrict__ ea,
                                                    const int* __restrict__ rj, const int* __restrict__ prj,
                                                    const int* __restrict__ off_c,
                                                    float* __restrict__ arj, unsigned short* __restrict__ ef,
                                                    int M) {
  int id = blockIdx.x;
  int xq = id & 7;
  int half = xq >> 2;
  int m = ((id >> 3) << 2) + (xq & 3);
  if (m >= M) return;
  int s = off_c[m], e_ = off_c[m + 1];
  int cnt = e_ - s;
  float eam = ea[m];
  int t = threadIdx.x, lane = t & 63, w = t >> 6;
  const unsigned short* xh = xl + half * 256;  // feature-half base

  __shared__ int sidx[512];
  __shared__ float swgt[512];
  __shared__ float pf[4][256];
  float acc[4] = {0, 0, 0, 0};

  if (cnt <= 512) {
    float mx = -3.402823466e38f;
    for (int j = t; j < cnt; j += 256) {
      int r = rj[s + j];
      float lg = lrelu(xa[r] + eam, 0.2f);
      sidx[j] = r;
      swgt[j] = lg;
      mx = fmaxf(mx, lg);
    }
    mx = blockReduceMax256(mx);
    float sum = 0.f;
    for (int j = t; j < cnt; j += 256) sum += expf(swgt[j] - mx);
    sum = blockReduceSum256(sum);
    float inv = 1.0f / fmaxf(sum, 1e-16f);
    for (int j = t; j < cnt; j += 256) {
      float a = expf(swgt[j] - mx) * inv;
      swgt[j] = a;
      if (half == 0) arj[prj[s + j]] = a;
    }
    __syncthreads();
    int j = w;
    for (; j + 16 <= cnt; j += 16) {
      int r0 = sidx[j], r1 = sidx[j + 4], r2 = sidx[j + 8], r3 = sidx[j + 12];
      float w0 = swgt[j], w1 = swgt[j + 4], w2 = swgt[j + 8], w3 = swgt[j + 12];
      bf16x4 v0 = *(const bf16x4*)(xh + (size_t)r0 * FDIM + lane * 4);
      bf16x4 v1 = *(const bf16x4*)(xh + (size_t)r1 * FDIM + lane * 4);
      bf16x4 v2 = *(const bf16x4*)(xh + (size_t)r2 * FDIM + lane * 4);
      bf16x4 v3 = *(const bf16x4*)(xh + (size_t)r3 * FDIM + lane * 4);
#pragma unroll
      for (int i = 0; i < 4; ++i) acc[i] = fmaf(w0, (float)v0[i], acc[i]);
#pragma unroll
      for (int i = 0; i < 4; ++i) acc[i] = fmaf(w1, (float)v1[i], acc[i]);
#pragma unroll
      for (int i = 0; i < 4; ++i) acc[i] = fmaf(w2, (float)v2[i], acc[i]);
#pragma unroll
      for (int i = 0; i < 4; ++i) acc[i] = fmaf(w3, (float)v3[i], acc[i]);
    }
    for (; j < cnt; j += 4) {
      int r = sidx[j];
      float wt = swgt[j];
      bf16x4 v = *(const bf16x4*)(xh + (size_t)r * FDIM + lane * 4);
#pragma unroll
      for (int i = 0; i < 4; ++i) acc[i] = fmaf(wt, (float)v[i], acc[i]);
    }
    __syncthreads();
  } else {
    float mx = -3.402823466e38f;
    for (int j = s + t; j < e_; j += 256) mx = fmaxf(mx, lrelu(xa[rj[j]] + eam, 0.2f));
    mx = blockReduceMax256(mx);
    float sum = 0.f;
    for (int j = s + t; j < e_; j += 256) sum += expf(lrelu(xa[rj[j]] + eam, 0.2f) - mx);
    sum = blockReduceSum256(sum);
    float inv = 1.0f / fmaxf(sum, 1e-16f);
    for (int base = 0; base < cnt; base += 512) {
      int n = min(512, cnt - base);
      for (int j = t; j < n; j += 256) {
        int g = s + base + j;
        int r = rj[g];
        float a = expf(lrelu(xa[r] + eam, 0.2f) - mx) * inv;
        sidx[j] = r;
        swgt[j] = a;
        if (half == 0) arj[prj[g]] = a;
      }
      __syncthreads();
      for (int j = w; j < n; j += 4) {
        int r = sidx[j];
        float wt = swgt[j];
        bf16x4 v = *(const bf16x4*)(xh + (size_t)r * FDIM + lane * 4);
#pragma unroll
        for (int i = 0; i < 4; ++i) acc[i] = fmaf(wt, (float)v[i], acc[i]);
      }
      __syncthreads();
    }
  }

  float binv = cnt > 0 ? 1.0f / (float)cnt : 0.0f;
#pragma unroll
  for (int i = 0; i < 4; ++i) pf[w][lane * 4 + i] = acc[i] * binv;
  __syncthreads();
  float v = pf[0][t] + pf[1][t] + pf[2][t] + pf[3][t];
  ef[(size_t)m * FDIM + half * 256 + t] = f2bf(v);
}

// ---------------- propagate 2 (hyperedges -> nodes), feature-half split ----------------
// Grid 2*ceil(N/4)*... : same decode; per-XCD ef working set = 2 MB (L2-resident).
__global__ __launch_bounds__(256) void k_prop_row(const unsigned short* __restrict__ ef,
                                                  const float* __restrict__ arj, const int* __restrict__ cj,
                                                  const int* __restrict__ off_r, const float* __restrict__ bias,
                                                  unsigned short* __restrict__ hb, int N) {
  int id = blockIdx.x;
  int xq = id & 7;
  int half = xq >> 2;
  int nB = ((id >> 3) << 2) + (xq & 3);
  if (nB >= N) return;
  int s = off_r[nB], e_ = off_r[nB + 1];
  int cnt = e_ - s;
  const unsigned short* eh = ef + half * 256;
  __shared__ int sidx[512];
  __shared__ float swgt[512];
  __shared__ float pf[4][256];
  int t = threadIdx.x, lane = t & 63, w = t >> 6;
  float acc[4] = {0, 0, 0, 0};
  for (int base = 0; base < cnt; base += 512) {
    int n = min(512, cnt - base);
    for (int j = t; j < n; j += 256) {
      sidx[j] = cj[s + base + j];
      swgt[j] = arj[s + base + j];
    }
    __syncthreads();
    int j = w;
    for (; j + 16 <= n; j += 16) {
      int r0 = sidx[j], r1 = sidx[j + 4], r2 = sidx[j + 8], r3 = sidx[j + 12];
      float w0 = swgt[j], w1 = swgt[j + 4], w2 = swgt[j + 8], w3 = swgt[j + 12];
      bf16x4 v0 = *(const bf16x4*)(eh + (size_t)r0 * FDIM + lane * 4);
      bf16x4 v1 = *(const bf16x4*)(eh + (size_t)r1 * FDIM + lane * 4);
      bf16x4 v2 = *(const bf16x4*)(eh + (size_t)r2 * FDIM + lane * 4);
      bf16x4 v3 = *(const bf16x4*)(eh + (size_t)r3 * FDIM + lane * 4);
#pragma unroll
      for (int i = 0; i < 4; ++i) acc[i] = fmaf(w0, (float)v0[i], acc[i]);
#pragma unroll
      for (int i = 0; i < 4; ++i) acc[i] = fmaf(w1, (float)v1[i], acc[i]);
#pragma unroll
      for (int i = 0; i < 4; ++i) acc[i] = fmaf(w2, (float)v2[i], acc[i]);
#pragma unroll
      for (int i = 0; i < 4; ++i) acc[i] = fmaf(w3, (float)v3[i], acc[i]);
    }
    for (; j < n; j += 4) {
      int r = sidx[j];
      float wt = swgt[j];
      bf16x4 v = *(const bf16x4*)(eh + (size_t)r * FDIM + lane * 4);
#pragma unroll
      for (int i = 0; i < 4; ++i) acc[i] = fmaf(wt, (float)v[i], acc[i]);
    }
    __syncthreads();
  }
  float dinv = cnt > 0 ? 1.0f / (float)cnt : 0.0f;
#pragma unroll
  for (int i = 0; i < 4; ++i) pf[w][lane * 4 + i] = acc[i] * dinv;
  __syncthreads();
  int f = half * 256 + t;
  float v = pf[0][t] + pf[1][t] + pf[2][t] + pf[3][t] + bias[f];
  hb[(size_t)nB * FDIM + f] = f2bf(v);
}

// ---------------- GraphNorm ----------------
__global__ __launch_bounds__(256) void k_stats(const unsigned short* __restrict__ hb, float* __restrict__ gsum,
                                               float* __restrict__ gsq, int N) {
  int t = threadIdx.x;
  float s0 = 0, q0 = 0, s1 = 0, q1 = 0;
  for (int r = blockIdx.x; r < N; r += gridDim.x) {
    unsigned int u = ((const unsigned int*)(hb + (size_t)r * FDIM))[t];
    float v0 = bf2f(u & 0xffffu), v1 = bf2f(u >> 16);
    s0 += v0; q0 = fmaf(v0, v0, q0);
    s1 += v1; q1 = fmaf(v1, v1, q1);
  }
  atomicAdd(&gsum[2 * t], s0);
  atomicAdd(&gsq[2 * t], q0);
  atomicAdd(&gsum[2 * t + 1], s1);
  atomicAdd(&gsq[2 * t + 1], q1);
}

__global__ __launch_bounds__(256) void k_napply(const unsigned short* __restrict__ hb,
                                                const float* __restrict__ gsum, const float* __restrict__ gsq,
                                                const float* __restrict__ ms, const float* __restrict__ wg,
                                                const float* __restrict__ b, unsigned short* __restrict__ hi,
                                                float invn, int total2) {
  int i = blockIdx.x * 256 + threadIdx.x;
  if (i < total2) {
    int f2 = i & 255;
    int f0 = 2 * f2, f1 = 2 * f2 + 1;
    float mean0 = gsum[f0] * invn, mean1 = gsum[f1] * invn;
    float m0 = ms[f0], m1 = ms[f1];
    float var0 = gsq[f0] * invn - (2.0f * m0 - m0 * m0) * mean0 * mean0;
    float var1 = gsq[f1] * invn - (2.0f * m1 - m1 * m1) * mean1 * mean1;
    float scl0 = wg[f0] * __frsqrt_rn(var0 + 1e-5f);
    float scl1 = wg[f1] * __frsqrt_rn(var1 + 1e-5f);
    unsigned int u = ((const unsigned int*)hb)[i];
    float v0 = bf2f(u & 0xffffu), v1 = bf2f(u >> 16);
    v0 = lrelu((v0 - m0 * mean0) * scl0 + b[f0], 0.01f);
    v1 = lrelu((v1 - m1 * mean1) * scl1 + b[f1], 0.01f);
    ((unsigned int*)hi)[i] = (unsigned int)f2bf(v0) | ((unsigned int)f2bf(v1) << 16);
  }
}

extern "C" void kernel_launch(void* const* d_in, const int* in_sizes, int n_in,
                              void* d_out, int out_size, void* d_ws, size_t ws_size,
                              hipStream_t stream) {
  const float* x      = (const float*)d_in[0];
  const int*   eidx   = (const int*)d_in[1];
  const float* eattr  = (const float*)d_in[2];
  const float* W1     = (const float*)d_in[3];
  const float* att1   = (const float*)d_in[4];
  const float* b1     = (const float*)d_in[5];
  const float* W2     = (const float*)d_in[6];
  const float* att2   = (const float*)d_in[7];
  const float* b2     = (const float*)d_in[8];
  const float* gn1_w  = (const float*)d_in[9];
  const float* gn1_b  = (const float*)d_in[10];
  const float* gn1_ms = (const float*)d_in[11];
  const float* gn2_w  = (const float*)d_in[12];
  const float* gn2_b  = (const float*)d_in[13];
  const float* gn2_ms = (const float*)d_in[14];
  const float* fc1_W  = (const float*)d_in[15];
  const float* fc1_b  = (const float*)d_in[16];
  const float* fc2_W  = (const float*)d_in[17];
  const float* fc2_b  = (const float*)d_in[18];
  const float* cls_W  = (const float*)d_in[19];
  const float* cls_b  = (const float*)d_in[20];
  float* logits = (float*)d_out;

  const int N = in_sizes[0] / FDIM;
  const int E = in_sizes[1] / 2;
  const int M = in_sizes[2] / FDIM;  // == 2048 (hist/scan/fill assume it)
  const int* row = eidx;
  const int* col = eidx + E;
  const size_t NS = (size_t)N * FDIM;
  const size_t MS = (size_t)M * FDIM;

  char* base = (char*)d_ws;
  auto alloc = [&](size_t bytes) { char* r = base; base += (bytes + 255) & ~(size_t)255; return r; };

  unsigned short* xhi = (unsigned short*)alloc(NS * 2);   // x-hi
  unsigned short* xh1 = (unsigned short*)alloc(NS * 2);   // hn1
  unsigned short* xh2 = (unsigned short*)alloc(NS * 2);   // hn2
  unsigned short* xl  = (unsigned short*)alloc(NS * 2);   // conv GEMM output, bf16
  unsigned short* hb  = (unsigned short*)alloc(NS * 2);   // pre-norm h, bf16
  unsigned short* ef  = (unsigned short*)alloc(MS * 2);
  unsigned short* w1th = (unsigned short*)alloc(FDIM * FDIM * 2);
  unsigned short* w2th = (unsigned short*)alloc(FDIM * FDIM * 2);
  unsigned short* f1th = (unsigned short*)alloc(FDIM * HIDDIM * 2);
  unsigned short* f1tl = (unsigned short*)alloc(FDIM * HIDDIM * 2);
  unsigned short* f2th = (unsigned short*)alloc(FDIM * HIDDIM * 2);
  unsigned short* f2tl = (unsigned short*)alloc(FDIM * HIDDIM * 2);
  float* wv1 = (float*)alloc(FDIM * 4);
  float* wv2 = (float*)alloc(FDIM * 4);
  float* ea1 = (float*)alloc((size_t)M * 4);
  float* ea2 = (float*)alloc((size_t)M * 4);
  float* arj = (float*)alloc((size_t)E * 4);
  int* off_r = (int*)alloc((size_t)(N + 1) * 4);
  int* off_c = (int*)alloc((size_t)(M + 1) * 4);
  int* gcur  = (int*)alloc((size_t)M * 4);
  int* rj    = (int*)alloc((size_t)E * 4);
  int* cj    = (int*)alloc((size_t)E * 4);
  int* prj   = (int*)alloc((size_t)E * 4);
  int* btot  = (int*)alloc(512 * 4);

  // ---- single contiguous zeroed region ----
  char* zstart = base;
  int* cnt_r = (int*)alloc((size_t)(2 * N + M) * 4);  // cnt_r | cur_r | cnt_c
  int* cur_r = cnt_r + N;
  int* cnt_c = cur_r + N;
  float* xa1 = (float*)alloc((size_t)N * 4);
  float* xa2 = (float*)alloc((size_t)N * 4);
  float* gsum1 = (float*)alloc(FDIM * 4);
  float* gsq1  = (float*)alloc(FDIM * 4);
  float* gsum2 = (float*)alloc(FDIM * 4);
  float* gsq2  = (float*)alloc(FDIM * 4);
  size_t zlen = (size_t)(base - zstart);
  hipMemsetAsync(zstart, 0, zlen, stream);
  hipMemsetAsync(logits, 0, (size_t)N * 2 * sizeof(float), stream);

  int nchunk = (E + HB - 1) / HB;
  int nbR = (N + SCH - 1) / SCH;
  k_hist2<<<HB, 256, 0, stream>>>(row, col, cnt_r, cnt_c, E, nchunk);
  k_scan_part<<<nbR, 256, 0, stream>>>(cnt_r, off_r, btot, N);
  k_scan_midcol<<<2, 256, 0, stream>>>(btot, nbR, cnt_c, off_c, gcur);
  k_scan_add<<<nbR, 256, 0, stream>>>(off_r, btot, N, nbR);
  k_fill3<<<HB, 256, 0, stream>>>(row, col, gcur, off_r, cur_r, prj, rj, cj, E, nchunk);

  k_hi<<<(int)((NS / 4 + 255) / 256), 256, 0, stream>>>(x, xhi, (int)(NS / 4));
  k_prep_w_hi2<<<dim3(FDIM / 16, FDIM / 16, 2), 256, 0, stream>>>(W1, w1th, W2, w2th, FDIM, FDIM);
  k_prep_w2<<<dim3(HIDDIM / 16, FDIM / 16, 2), 256, 0, stream>>>(fc1_W, f1th, f1tl, fc2_W, f2th, f2tl, FDIM, HIDDIM);
  k_wv2<<<dim3(FDIM / 4, 2), 256, 0, stream>>>(W1, att1 + FDIM, W2, att2 + FDIM, wv1, wv2);
  k_ea2<<<(M + 3) / 4, 256, 0, stream>>>(eattr, wv1, wv2, ea1, ea2, M);

  int gN128 = (N + 127) / 128;
  int nPpad4 = ((gN128 + 7) / 8) * 8 * 4;  // XCD-swizzled 1D GEMM grid
  int gPC = ((M + 3) / 4) * 8;             // prop_col: 2*M half-split blocks
  int gPR = ((N + 3) / 4) * 8;             // prop_row: 2*N half-split blocks
  int napply_grid = (int)((NS / 2 + 255) / 256);
  float invn = 1.0f / (float)N;

  // ---- conv1 ----
  gemm_conv<<<nPpad4, 256, 0, stream>>>(xhi, w1th, xl, att1, xa1, N, FDIM, FDIM, gN128);
  k_prop_col_f<<<gPC, 256, 0, stream>>>(xl, xa1, ea1, rj, prj, off_c, arj, ef, M);
  k_prop_row<<<gPR, 256, 0, stream>>>(ef, arj, cj, off_r, b1, hb, N);
  k_stats<<<256, 256, 0, stream>>>(hb, gsum1, gsq1, N);
  k_napply<<<napply_grid, 256, 0, stream>>>(hb, gsum1, gsq1, gn1_ms, gn1_w, gn1_b, xh1, invn, (int)(NS / 2));

  // ---- conv2 ----
  gemm_conv<<<nPpad4, 256, 0, stream>>>(xh1, w2th, xl, att2, xa2, N, FDIM, FDIM, gN128);
  k_prop_col_f<<<gPC, 256, 0, stream>>>(xl, xa2, ea2, rj, prj, off_c, arj, ef, M);
  k_prop_row<<<gPR, 256, 0, stream>>>(ef, arj, cj, off_r, b2, hb, N);
  k_stats<<<256, 256, 0, stream>>>(hb, gsum2, gsq2, N);
  k_napply<<<napply_grid, 256, 0, stream>>>(hb, gsum2, gsq2, gn2_ms, gn2_w, gn2_b, xh2, invn, (int)(NS / 2));

  // ---- fc1 + fc2 + classifier, fused ----
  gemm_fc_cls<<<nPpad4, 256, 0, stream>>>(xh1, f1th, f1tl, fc1_b,
                                          xh2, f2th, f2tl, fc2_b,
                                          cls_W, cls_b, logits, N, FDIM, gN128);
}

// Round 13
// 521.341 us; speedup vs baseline: 1.0763x; 1.0763x over previous
//
#include <hip/hip_runtime.h>
#include <math.h>

#define FDIM 512
#define HIDDIM 256
#define HB 128   // edge-chunk blocks for hist/fill
#define SCH 1024 // elements per scan-part block
#define LDSK 32  // K-shorts per LDS row (no pad: required by global_load_lds layout)

typedef __bf16 bf16x8 __attribute__((ext_vector_type(8)));
typedef __bf16 bf16x4 __attribute__((ext_vector_type(4)));
typedef float floatx4 __attribute__((ext_vector_type(4)));

__device__ __forceinline__ float lrelu(float x, float s) { return x >= 0.0f ? x : s * x; }

__device__ __forceinline__ float bf2f(unsigned int u) {
  union { float f; unsigned int i; } v; v.i = u << 16; return v.f;
}
__device__ __forceinline__ unsigned short f2bf(float f) {
  union { float f; unsigned int u; } v; v.f = f;
  unsigned int x = v.u;
  return (unsigned short)((x + 0x7fffu + ((x >> 16) & 1u)) >> 16);
}

__device__ __forceinline__ void async_copy16(const unsigned short* g, unsigned short* l) {
  __builtin_amdgcn_global_load_lds((const __attribute__((address_space(1))) unsigned int*)g,
                                   (__attribute__((address_space(3))) unsigned int*)l, 16, 0, 0);
}

__device__ __forceinline__ float waveReduceSum(float v) {
#pragma unroll
  for (int o = 32; o; o >>= 1) v += __shfl_down(v, o, 64);
  return v;
}

__device__ __forceinline__ float blockReduceSum256(float v) {
  __shared__ float sm[4];
  int lane = threadIdx.x & 63, w = threadIdx.x >> 6;
  v = waveReduceSum(v);
  __syncthreads();
  if (lane == 0) sm[w] = v;
  __syncthreads();
  return sm[0] + sm[1] + sm[2] + sm[3];
}

__device__ __forceinline__ float blockReduceMax256(float v) {
  __shared__ float sm[4];
  int lane = threadIdx.x & 63, w = threadIdx.x >> 6;
#pragma unroll
  for (int o = 32; o; o >>= 1) v = fmaxf(v, __shfl_down(v, o, 64));
  __syncthreads();
  if (lane == 0) sm[w] = v;
  __syncthreads();
  return fmaxf(fmaxf(sm[0], sm[1]), fmaxf(sm[2], sm[3]));
}

// ---------------- CSR build ----------------
__global__ __launch_bounds__(256) void k_hist2(const int* __restrict__ row, const int* __restrict__ col,
                                               int* __restrict__ cnt_r, int* __restrict__ cnt_c,
                                               int E, int nchunk) {
  __shared__ int h[2048];
  int b = blockIdx.x, t = threadIdx.x;
  for (int i = t; i < 2048; i += 256) h[i] = 0;
  __syncthreads();
  int s = b * nchunk, e = min(E, s + nchunk);
  for (int j = s + t; j < e; j += 256) {
    atomicAdd(&h[col[j]], 1);
    atomicAdd(&cnt_r[row[j]], 1);
  }
  __syncthreads();
  for (int i = t; i < 2048; i += 256) {
    int v = h[i];
    if (v) atomicAdd(&cnt_c[i], v);
  }
}

__global__ __launch_bounds__(256) void k_scan_part(const int* __restrict__ cnt, int* __restrict__ off,
                                                   int* __restrict__ btot, int n) {
  int b = blockIdx.x, t = threadIdx.x;
  int base = b * SCH + t * 4;
  int v[4];
#pragma unroll
  for (int i = 0; i < 4; ++i) v[i] = (base + i < n) ? cnt[base + i] : 0;
  int s = v[0] + v[1] + v[2] + v[3];
  int lane = t & 63, w = t >> 6;
  int x = s;
#pragma unroll
  for (int o = 1; o < 64; o <<= 1) {
    int y = __shfl_up(x, o, 64);
    if (lane >= o) x += y;
  }
  __shared__ int ws[4];
  if (lane == 63) ws[w] = x;
  __syncthreads();
  int wpre = 0;
  for (int i = 0; i < w; ++i) wpre += ws[i];
  int run = wpre + x - s;
#pragma unroll
  for (int i = 0; i < 4; ++i) {
    if (base + i < n) off[base + i] = run;
    run += v[i];
  }
  if (t == 255) btot[b] = wpre + x;
}

// block 0: exclusive-scan btot (row mid-scan). block 1: 2048-col scan -> off_c, gcur.
__global__ __launch_bounds__(256) void k_scan_midcol(int* __restrict__ btot, int nb,
                                                     const int* __restrict__ cnt_c, int* __restrict__ off_c,
                                                     int* __restrict__ gcur) {
  int t = threadIdx.x, lane = t & 63, w = t >> 6;
  __shared__ int ws[4];
  if (blockIdx.x == 0) {
    int v = (t < nb) ? btot[t] : 0;
    int x = v;
#pragma unroll
    for (int o = 1; o < 64; o <<= 1) {
      int y = __shfl_up(x, o, 64);
      if (lane >= o) x += y;
    }
    if (lane == 63) ws[w] = x;
    __syncthreads();
    int wpre = 0;
    for (int i = 0; i < w; ++i) wpre += ws[i];
    if (t < nb) btot[t] = wpre + x - v;
    if (t == 255) btot[nb] = wpre + x;
  } else {
    int base = t * 8;
    int v[8];
#pragma unroll
    for (int i = 0; i < 8; ++i) v[i] = cnt_c[base + i];
    int s = 0;
#pragma unroll
    for (int i = 0; i < 8; ++i) s += v[i];
    int x = s;
#pragma unroll
    for (int o = 1; o < 64; o <<= 1) {
      int y = __shfl_up(x, o, 64);
      if (lane >= o) x += y;
    }
    if (lane == 63) ws[w] = x;
    __syncthreads();
    int wpre = 0;
    for (int i = 0; i < w; ++i) wpre += ws[i];
    int run = wpre + x - s;
#pragma unroll
    for (int i = 0; i < 8; ++i) {
      off_c[base + i] = run;
      gcur[base + i] = run;
      run += v[i];
    }
    if (t == 255) off_c[2048] = wpre + x;
  }
}

__global__ __launch_bounds__(256) void k_scan_add(int* __restrict__ off, const int* __restrict__ btot,
                                                  int n, int nb) {
  int b = blockIdx.x, t = threadIdx.x;
  int base = b * SCH + t * 4;
  int add = btot[b];
#pragma unroll
  for (int i = 0; i < 4; ++i)
    if (base + i < n) off[base + i] += add;
  if (b == 0 && t == 0) off[n] = btot[nb];
}

// fill: col side via LDS cursors + bulk reservation; writes rj and prj, cj for prop_row.
__global__ __launch_bounds__(256) void k_fill3(const int* __restrict__ row, const int* __restrict__ col,
                                               int* __restrict__ gcur, const int* __restrict__ off_r,
                                               int* __restrict__ cur_r, int* __restrict__ prj,
                                               int* __restrict__ rj, int* __restrict__ cj,
                                               int E, int nchunk) {
  __shared__ int h[2048];
  __shared__ int lbase[2048];
  int b = blockIdx.x, t = threadIdx.x;
  for (int i = t; i < 2048; i += 256) h[i] = 0;
  __syncthreads();
  int s = b * nchunk, e = min(E, s + nchunk);
  for (int j = s + t; j < e; j += 256) atomicAdd(&h[col[j]], 1);
  __syncthreads();
  for (int i = t; i < 2048; i += 256) {
    int c = h[i];
    lbase[i] = c ? atomicAdd(&gcur[i], c) : 0;
    h[i] = 0;
  }
  __syncthreads();
  for (int j = s + t; j < e; j += 256) {
    int r = row[j], c = col[j];
    int slot_c = lbase[c] + atomicAdd(&h[c], 1);
    int slot_r = off_r[r] + atomicAdd(&cur_r[r], 1);
    rj[slot_c] = r;
    prj[slot_c] = slot_r;
    cj[slot_r] = c;
  }
}

// ---------------- conversions ----------------
__global__ __launch_bounds__(256) void k_hi(const float* __restrict__ A, unsigned short* __restrict__ hi, int n4) {
  int i = blockIdx.x * 256 + threadIdx.x;
  if (i < n4) {
    float4 v = ((const float4*)A)[i];
    ushort4 h;
    h.x = f2bf(v.x); h.y = f2bf(v.y); h.z = f2bf(v.z); h.w = f2bf(v.w);
    ((ushort4*)hi)[i] = h;
  }
}

__global__ __launch_bounds__(256) void k_prep_w_hi2(const float* __restrict__ W1, unsigned short* __restrict__ t1,
                                                    const float* __restrict__ W2, unsigned short* __restrict__ t2,
                                                    int K, int Nc) {
  const float* W = blockIdx.z ? W2 : W1;
  unsigned short* th = blockIdx.z ? t2 : t1;
  int n = blockIdx.x * 16 + (threadIdx.x & 15);
  int k = blockIdx.y * 16 + (threadIdx.x >> 4);
  th[(size_t)n * K + k] = f2bf(W[(size_t)k * Nc + n]);
}

__global__ __launch_bounds__(256) void k_prep_w2(const float* __restrict__ Wa, unsigned short* __restrict__ tha,
                                                 unsigned short* __restrict__ tla, const float* __restrict__ Wb,
                                                 unsigned short* __restrict__ thb, unsigned short* __restrict__ tlb,
                                                 int K, int Nc) {
  const float* W = blockIdx.z ? Wb : Wa;
  unsigned short* th = blockIdx.z ? thb : tha;
  unsigned short* tl = blockIdx.z ? tlb : tla;
  int n = blockIdx.x * 16 + (threadIdx.x & 15);
  int k = blockIdx.y * 16 + (threadIdx.x >> 4);
  float v = W[(size_t)k * Nc + n];
  unsigned short h = f2bf(v);
  unsigned short l = f2bf(v - bf2f(h));
  th[(size_t)n * K + k] = h;
  tl[(size_t)n * K + k] = l;
}

// ---------------- attention matvecs ----------------
__global__ __launch_bounds__(256) void k_wv2(const float* __restrict__ W1, const float* __restrict__ a1,
                                             const float* __restrict__ W2, const float* __restrict__ a2,
                                             float* __restrict__ wv1, float* __restrict__ wv2) {
  int lane = threadIdx.x & 63, w = threadIdx.x >> 6;
  int k = blockIdx.x * 4 + w;
  const float* W = blockIdx.y ? W2 : W1;
  const float* a = blockIdx.y ? a2 : a1;
  float* wv = blockIdx.y ? wv2 : wv1;
  float s = 0.f;
  for (int f = lane; f < FDIM; f += 64) s = fmaf(W[(size_t)k * FDIM + f], a[f], s);
  s = waveReduceSum(s);
  if (lane == 0) wv[k] = s;
}

__global__ __launch_bounds__(256) void k_ea2(const float* __restrict__ X, const float* __restrict__ wv1,
                                             const float* __restrict__ wv2, float* __restrict__ ea1,
                                             float* __restrict__ ea2, int Mr) {
  int lane = threadIdx.x & 63, w = threadIdx.x >> 6;
  int m = blockIdx.x * 4 + w;
  if (m < Mr) {
    float s1 = 0.f, s2 = 0.f;
    for (int f = lane; f < FDIM; f += 64) {
      float v = X[(size_t)m * FDIM + f];
      s1 = fmaf(v, wv1[f], s1);
      s2 = fmaf(v, wv2[f], s2);
    }
    s1 = waveReduceSum(s1);
    s2 = waveReduceSum(s2);
    if (lane == 0) { ea1[m] = s1; ea2[m] = s2; }
  }
}

// XCD-aware decode for GEMMs: panel = (id>>5)*8 + (id&7), c = (id>>3)&3.
__device__ __forceinline__ bool xcd_decode(int id, int nP, int& panel, int& c) {
  panel = ((id >> 5) << 3) + (id & 7);
  c = (id >> 3) & 3;
  return panel < nP;
}

// ---------------- conv GEMM: plain bf16, async staging, fused att-rowdot ----------------
__global__ __launch_bounds__(256, 1) void gemm_conv(const unsigned short* __restrict__ Ah,
                                                    const unsigned short* __restrict__ Bth,
                                                    unsigned short* __restrict__ Cb,
                                                    const float* __restrict__ att, float* __restrict__ xa,
                                                    int Mr, int K, int Nc, int nP) {
  int panel, cblk;
  if (!xcd_decode(blockIdx.x, nP, panel, cblk)) return;
  __shared__ unsigned short lds[2 * 128 * LDSK];
  int tid = threadIdx.x, lane = tid & 63, w = tid >> 6;
  int wr = w >> 1, wc = w & 1;
  int rowB = panel * 128, colB = cblk * 128;

  const unsigned short* src = (w < 2) ? Ah : Bth;
  int baseRow = ((w < 2) ? rowB : colB) + 64 * (w & 1);
  int maxRow = (w < 2) ? (Mr - 1) : (Nc - 1);
  int slr = lane >> 2, slc = lane & 3;
  unsigned short* dstBase = &lds[((w >> 1) * 128 + (w & 1) * 64) * LDSK];

  size_t gro[4];
#pragma unroll
  for (int seg = 0; seg < 4; ++seg) {
    int rg = baseRow + seg * 16 + slr;
    if (rg > maxRow) rg = maxRow;
    gro[seg] = (size_t)rg * K + slc * 8;
  }

  floatx4 zero4 = {0.f, 0.f, 0.f, 0.f};
  floatx4 acc[4][4];
#pragma unroll
  for (int i = 0; i < 4; ++i)
#pragma unroll
    for (int j = 0; j < 4; ++j) acc[i][j] = zero4;

  int fr = lane & 15, fq = lane >> 4;
  int offA = (wr * 64 + fr) * LDSK + fq * 8;
  int offB = 128 * LDSK + (wc * 64 + fr) * LDSK + fq * 8;

  for (int k0 = 0; k0 < K; k0 += 32) {
#pragma unroll
    for (int seg = 0; seg < 4; ++seg) async_copy16(src + gro[seg] + k0, dstBase + seg * 16 * LDSK);
    __syncthreads();
    bf16x8 a[4], b[4];
#pragma unroll
    for (int t = 0; t < 4; ++t) {
      a[t] = *(const bf16x8*)(&lds[offA + t * 16 * LDSK]);
      b[t] = *(const bf16x8*)(&lds[offB + t * 16 * LDSK]);
    }
#pragma unroll
    for (int ti = 0; ti < 4; ++ti)
#pragma unroll
      for (int tj = 0; tj < 4; ++tj)
        acc[ti][tj] = __builtin_amdgcn_mfma_f32_16x16x32_bf16(a[ti], b[tj], acc[ti][tj], 0, 0, 0);
    __syncthreads();
  }

  int colL = colB + wc * 64 + fr;
  int rowL = rowB + wr * 64 + fq * 4;
  float attv[4];
#pragma unroll
  for (int tj = 0; tj < 4; ++tj) attv[tj] = att[colL + tj * 16];
#pragma unroll
  for (int ti = 0; ti < 4; ++ti) {
#pragma unroll
    for (int r = 0; r < 4; ++r) {
      int rr = rowL + ti * 16 + r;
      if (rr < Mr) {
        float dot = 0.f;
#pragma unroll
        for (int tj = 0; tj < 4; ++tj) {
          float v = acc[ti][tj][r];
          Cb[(size_t)rr * Nc + colL + tj * 16] = f2bf(v);
          dot = fmaf(v, attv[tj], dot);
        }
#pragma unroll
        for (int o = 1; o < 16; o <<= 1) dot += __shfl_xor(dot, o, 64);
        if ((lane & 15) == 0) atomicAdd(&xa[rr], dot);
      }
    }
  }
}

// ---------------- fused FC1+FC2+classifier (XCD-swizzled) ----------------
__global__ __launch_bounds__(256, 1) void gemm_fc_cls(const unsigned short* __restrict__ A1,
                                                      const unsigned short* __restrict__ B1h,
                                                      const unsigned short* __restrict__ B1l,
                                                      const float* __restrict__ b1,
                                                      const unsigned short* __restrict__ A2,
                                                      const unsigned short* __restrict__ B2h,
                                                      const unsigned short* __restrict__ B2l,
                                                      const float* __restrict__ b2,
                                                      const float* __restrict__ clsW, const float* __restrict__ clsb,
                                                      float* __restrict__ logits, int Mr, int K, int nP) {
  int panel, cblk;
  if (!xcd_decode(blockIdx.x, nP, panel, cblk)) return;
  __shared__ unsigned short lds[(128 + 2 * 64) * LDSK];
  int tid = threadIdx.x, lane = tid & 63, w = tid >> 6;
  int wr = w >> 1, wc = w & 1;
  int rowB = panel * 128, colB = cblk * 64;

  int slr = lane >> 2, slc = lane & 3;
  int baseRow = (w < 2) ? (rowB + 64 * w) : colB;
  int maxRow = (w < 2) ? (Mr - 1) : (HIDDIM - 1);
  unsigned short* dstBase = &lds[w * 64 * LDSK];

  size_t gro[4];
#pragma unroll
  for (int seg = 0; seg < 4; ++seg) {
    int rg = baseRow + seg * 16 + slr;
    if (rg > maxRow) rg = maxRow;
    gro[seg] = (size_t)rg * K + slc * 8;
  }

  int fr = lane & 15, fq = lane >> 4;
  int offA = (wr * 64 + fr) * LDSK + fq * 8;
  int offBh = (128 + wc * 32 + fr) * LDSK + fq * 8;
  int offBl = offBh + 64 * LDSK;

  floatx4 zero4 = {0.f, 0.f, 0.f, 0.f};
  floatx4 acc1[4][2], acc2[4][2];
#pragma unroll
  for (int i = 0; i < 4; ++i) {
    acc1[i][0] = zero4; acc1[i][1] = zero4;
    acc2[i][0] = zero4; acc2[i][1] = zero4;
  }

#pragma unroll
  for (int L = 0; L < 2; ++L) {
    const unsigned short* src =
        (L == 0) ? ((w < 2) ? A1 : (w == 2) ? B1h : B1l)
                 : ((w < 2) ? A2 : (w == 2) ? B2h : B2l);
    for (int k0 = 0; k0 < K; k0 += 32) {
#pragma unroll
      for (int seg = 0; seg < 4; ++seg) async_copy16(src + gro[seg] + k0, dstBase + seg * 16 * LDSK);
      __syncthreads();
      bf16x8 a[4], bh[2], bl[2];
#pragma unroll
      for (int t = 0; t < 4; ++t) a[t] = *(const bf16x8*)(&lds[offA + t * 16 * LDSK]);
#pragma unroll
      for (int t = 0; t < 2; ++t) {
        bh[t] = *(const bf16x8*)(&lds[offBh + t * 16 * LDSK]);
        bl[t] = *(const bf16x8*)(&lds[offBl + t * 16 * LDSK]);
      }
      if (L == 0) {
#pragma unroll
        for (int ti = 0; ti < 4; ++ti)
#pragma unroll
          for (int tj = 0; tj < 2; ++tj) {
            acc1[ti][tj] = __builtin_amdgcn_mfma_f32_16x16x32_bf16(a[ti], bh[tj], acc1[ti][tj], 0, 0, 0);
            acc1[ti][tj] = __builtin_amdgcn_mfma_f32_16x16x32_bf16(a[ti], bl[tj], acc1[ti][tj], 0, 0, 0);
          }
      } else {
#pragma unroll
        for (int ti = 0; ti < 4; ++ti)
#pragma unroll
          for (int tj = 0; tj < 2; ++tj) {
            acc2[ti][tj] = __builtin_amdgcn_mfma_f32_16x16x32_bf16(a[ti], bh[tj], acc2[ti][tj], 0, 0, 0);
            acc2[ti][tj] = __builtin_amdgcn_mfma_f32_16x16x32_bf16(a[ti], bl[tj], acc2[ti][tj], 0, 0, 0);
          }
      }
      __syncthreads();
    }
  }

  int colL = colB + wc * 32 + fr;
  int rowL = rowB + wr * 64 + fq * 4;
  float cw0[2], cw1[2], bb1[2], bb2[2];
#pragma unroll
  for (int tj = 0; tj < 2; ++tj) {
    int c = colL + tj * 16;
    cw0[tj] = clsW[2 * c];
    cw1[tj] = clsW[2 * c + 1];
    bb1[tj] = b1[c];
    bb2[tj] = b2[c];
  }
  bool addBias = (cblk == 0 && wc == 0);
  float cb0 = clsb[0], cb1 = clsb[1];
#pragma unroll
  for (int ti = 0; ti < 4; ++ti) {
#pragma unroll
    for (int r = 0; r < 4; ++r) {
      int rr = rowL + ti * 16 + r;
      if (rr < Mr) {
        float d0 = 0.f, d1 = 0.f;
#pragma unroll
        for (int tj = 0; tj < 2; ++tj) {
          float v = lrelu(acc1[ti][tj][r] + bb1[tj], 0.01f) + lrelu(acc2[ti][tj][r] + bb2[tj], 0.01f);
          d0 = fmaf(v, cw0[tj], d0);
          d1 = fmaf(v, cw1[tj], d1);
        }
#pragma unroll
        for (int o = 1; o < 16; o <<= 1) {
          d0 += __shfl_xor(d0, o, 64);
          d1 += __shfl_xor(d1, o, 64);
        }
        if ((lane & 15) == 0) {
          if (addBias) { d0 += cb0; d1 += cb1; }
          atomicAdd(&logits[2 * (size_t)rr], d0);
          atomicAdd(&logits[2 * (size_t)rr + 1], d1);
        }
      }
    }
  }
}

// ---------------- fused softmax + propagate (nodes -> hyperedges), feature-half split ----
__global__ __launch_bounds__(256) void k_prop_col_f(const unsigned short* __restrict__ xl,
                                                    const float* __restrict__ xa, const float* __restrict__ ea,
                                                    const int* __restrict__ rj, const int* __restrict__ prj,
                                                    const int* __restrict__ off_c,
                                                    float* __restrict__ arj, unsigned short* __restrict__ ef,
                                                    int M) {
  int id = blockIdx.x;
  int xq = id & 7;
  int half = xq >> 2;
  int m = ((id >> 3) << 2) + (xq & 3);
  if (m >= M) return;
  int s = off_c[m], e_ = off_c[m + 1];
  int cnt = e_ - s;
  float eam = ea[m];
  int t = threadIdx.x, lane = t & 63, w = t >> 6;
  const unsigned short* xh = xl + half * 256;  // feature-half base

  __shared__ int sidx[512];
  __shared__ float swgt[512];
  __shared__ float pf[4][256];
  float acc[4] = {0, 0, 0, 0};

  if (cnt <= 512) {
    float mx = -3.402823466e38f;
    for (int j = t; j < cnt; j += 256) {
      int r = rj[s + j];
      float lg = lrelu(xa[r] + eam, 0.2f);
      sidx[j] = r;
      swgt[j] = lg;
      mx = fmaxf(mx, lg);
    }
    mx = blockReduceMax256(mx);
    float sum = 0.f;
    for (int j = t; j < cnt; j += 256) sum += expf(swgt[j] - mx);
    sum = blockReduceSum256(sum);
    float inv = 1.0f / fmaxf(sum, 1e-16f);
    for (int j = t; j < cnt; j += 256) {
      float a = expf(swgt[j] - mx) * inv;
      swgt[j] = a;
      if (half == 0) arj[prj[s + j]] = a;
    }
    __syncthreads();
    int j = w;
    for (; j + 16 <= cnt; j += 16) {
      int r0 = sidx[j], r1 = sidx[j + 4], r2 = sidx[j + 8], r3 = sidx[j + 12];
      float w0 = swgt[j], w1 = swgt[j + 4], w2 = swgt[j + 8], w3 = swgt[j + 12];
      bf16x4 v0 = *(const bf16x4*)(xh + (size_t)r0 * FDIM + lane * 4);
      bf16x4 v1 = *(const bf16x4*)(xh + (size_t)r1 * FDIM + lane * 4);
      bf16x4 v2 = *(const bf16x4*)(xh + (size_t)r2 * FDIM + lane * 4);
      bf16x4 v3 = *(const bf16x4*)(xh + (size_t)r3 * FDIM + lane * 4);
#pragma unroll
      for (int i = 0; i < 4; ++i) acc[i] = fmaf(w0, (float)v0[i], acc[i]);
#pragma unroll
      for (int i = 0; i < 4; ++i) acc[i] = fmaf(w1, (float)v1[i], acc[i]);
#pragma unroll
      for (int i = 0; i < 4; ++i) acc[i] = fmaf(w2, (float)v2[i], acc[i]);
#pragma unroll
      for (int i = 0; i < 4; ++i) acc[i] = fmaf(w3, (float)v3[i], acc[i]);
    }
    for (; j < cnt; j += 4) {
      int r = sidx[j];
      float wt = swgt[j];
      bf16x4 v = *(const bf16x4*)(xh + (size_t)r * FDIM + lane * 4);
#pragma unroll
      for (int i = 0; i < 4; ++i) acc[i] = fmaf(wt, (float)v[i], acc[i]);
    }
    __syncthreads();
  } else {
    float mx = -3.402823466e38f;
    for (int j = s + t; j < e_; j += 256) mx = fmaxf(mx, lrelu(xa[rj[j]] + eam, 0.2f));
    mx = blockReduceMax256(mx);
    float sum = 0.f;
    for (int j = s + t; j < e_; j += 256) sum += expf(lrelu(xa[rj[j]] + eam, 0.2f) - mx);
    sum = blockReduceSum256(sum);
    float inv = 1.0f / fmaxf(sum, 1e-16f);
    for (int base = 0; base < cnt; base += 512) {
      int n = min(512, cnt - base);
      for (int j = t; j < n; j += 256) {
        int g = s + base + j;
        int r = rj[g];
        float a = expf(lrelu(xa[r] + eam, 0.2f) - mx) * inv;
        sidx[j] = r;
        swgt[j] = a;
        if (half == 0) arj[prj[g]] = a;
      }
      __syncthreads();
      for (int j = w; j < n; j += 4) {
        int r = sidx[j];
        float wt = swgt[j];
        bf16x4 v = *(const bf16x4*)(xh + (size_t)r * FDIM + lane * 4);
#pragma unroll
        for (int i = 0; i < 4; ++i) acc[i] = fmaf(wt, (float)v[i], acc[i]);
      }
      __syncthreads();
    }
  }

  float binv = cnt > 0 ? 1.0f / (float)cnt : 0.0f;
#pragma unroll
  for (int i = 0; i < 4; ++i) pf[w][lane * 4 + i] = acc[i] * binv;
  __syncthreads();
  float v = pf[0][t] + pf[1][t] + pf[2][t] + pf[3][t];
  ef[(size_t)m * FDIM + half * 256 + t] = f2bf(v);
}

// ---------------- propagate 2 (hyperedges -> nodes), FULL-ROW (deg~16: low overhead) ----
__global__ __launch_bounds__(256) void k_prop_row(const unsigned short* __restrict__ ef,
                                                  const float* __restrict__ arj, const int* __restrict__ cj,
                                                  const int* __restrict__ off_r, const float* __restrict__ bias,
                                                  unsigned short* __restrict__ hb) {
  int nB = blockIdx.x;
  int s = off_r[nB], e_ = off_r[nB + 1];
  int cnt = e_ - s;
  __shared__ int sidx[512];
  __shared__ float swgt[512];
  __shared__ float pf[4][512];
  int t = threadIdx.x, lane = t & 63, w = t >> 6;
  float acc[8] = {0, 0, 0, 0, 0, 0, 0, 0};
  for (int base = 0; base < cnt; base += 512) {
    int n = min(512, cnt - base);
    for (int j = t; j < n; j += 256) {
      sidx[j] = cj[s + base + j];
      swgt[j] = arj[s + base + j];
    }
    __syncthreads();
    int j = w;
    for (; j + 8 <= n; j += 8) {
      int r0 = sidx[j], r1 = sidx[j + 4];
      float w0 = swgt[j], w1 = swgt[j + 4];
      bf16x8 v0 = *(const bf16x8*)(ef + (size_t)r0 * FDIM + lane * 8);
      bf16x8 v1 = *(const bf16x8*)(ef + (size_t)r1 * FDIM + lane * 8);
#pragma unroll
      for (int i = 0; i < 8; ++i) acc[i] = fmaf(w0, (float)v0[i], acc[i]);
#pragma unroll
      for (int i = 0; i < 8; ++i) acc[i] = fmaf(w1, (float)v1[i], acc[i]);
    }
    for (; j < n; j += 4) {
      int r = sidx[j];
      float wt = swgt[j];
      bf16x8 v = *(const bf16x8*)(ef + (size_t)r * FDIM + lane * 8);
#pragma unroll
      for (int i = 0; i < 8; ++i) acc[i] = fmaf(wt, (float)v[i], acc[i]);
    }
    __syncthreads();
  }
  float dinv = cnt > 0 ? 1.0f / (float)cnt : 0.0f;
#pragma unroll
  for (int i = 0; i < 8; i += 2) *(float2*)&pf[w][lane * 8 + i] = make_float2(acc[i] * dinv, acc[i + 1] * dinv);
  __syncthreads();
  float2 r0 = ((const float2*)pf[0])[t], r1 = ((const float2*)pf[1])[t];
  float2 r2 = ((const float2*)pf[2])[t], r3 = ((const float2*)pf[3])[t];
  float a0 = r0.x + r1.x + r2.x + r3.x + bias[2 * t];
  float a1 = r0.y + r1.y + r2.y + r3.y + bias[2 * t + 1];
  unsigned int o = (unsigned int)f2bf(a0) | ((unsigned int)f2bf(a1) << 16);
  ((unsigned int*)(hb + (size_t)nB * FDIM))[t] = o;
}

// ---------------- GraphNorm ----------------
__global__ __launch_bounds__(256) void k_stats(const unsigned short* __restrict__ hb, float* __restrict__ gsum,
                                               float* __restrict__ gsq, int N) {
  int t = threadIdx.x;
  float s0 = 0, q0 = 0, s1 = 0, q1 = 0;
  for (int r = blockIdx.x; r < N; r += gridDim.x) {
    unsigned int u = ((const unsigned int*)(hb + (size_t)r * FDIM))[t];
    float v0 = bf2f(u & 0xffffu), v1 = bf2f(u >> 16);
    s0 += v0; q0 = fmaf(v0, v0, q0);
    s1 += v1; q1 = fmaf(v1, v1, q1);
  }
  atomicAdd(&gsum[2 * t], s0);
  atomicAdd(&gsq[2 * t], q0);
  atomicAdd(&gsum[2 * t + 1], s1);
  atomicAdd(&gsq[2 * t + 1], q1);
}

__global__ __launch_bounds__(256) void k_napply(const unsigned short* __restrict__ hb,
                                                const float* __restrict__ gsum, const float* __restrict__ gsq,
                                                const float* __restrict__ ms, const float* __restrict__ wg,
                                                const float* __restrict__ b, unsigned short* __restrict__ hi,
                                                float invn, int total2) {
  int i = blockIdx.x * 256 + threadIdx.x;
  if (i < total2) {
    int f2 = i & 255;
    int f0 = 2 * f2, f1 = 2 * f2 + 1;
    float mean0 = gsum[f0] * invn, mean1 = gsum[f1] * invn;
    float m0 = ms[f0], m1 = ms[f1];
    float var0 = gsq[f0] * invn - (2.0f * m0 - m0 * m0) * mean0 * mean0;
    float var1 = gsq[f1] * invn - (2.0f * m1 - m1 * m1) * mean1 * mean1;
    float scl0 = wg[f0] * __frsqrt_rn(var0 + 1e-5f);
    float scl1 = wg[f1] * __frsqrt_rn(var1 + 1e-5f);
    unsigned int u = ((const unsigned int*)hb)[i];
    float v0 = bf2f(u & 0xffffu), v1 = bf2f(u >> 16);
    v0 = lrelu((v0 - m0 * mean0) * scl0 + b[f0], 0.01f);
    v1 = lrelu((v1 - m1 * mean1) * scl1 + b[f1], 0.01f);
    ((unsigned int*)hi)[i] = (unsigned int)f2bf(v0) | ((unsigned int)f2bf(v1) << 16);
  }
}

extern "C" void kernel_launch(void* const* d_in, const int* in_sizes, int n_in,
                              void* d_out, int out_size, void* d_ws, size_t ws_size,
                              hipStream_t stream) {
  const float* x      = (const float*)d_in[0];
  const int*   eidx   = (const int*)d_in[1];
  const float* eattr  = (const float*)d_in[2];
  const float* W1     = (const float*)d_in[3];
  const float* att1   = (const float*)d_in[4];
  const float* b1     = (const float*)d_in[5];
  const float* W2     = (const float*)d_in[6];
  const float* att2   = (const float*)d_in[7];
  const float* b2     = (const float*)d_in[8];
  const float* gn1_w  = (const float*)d_in[9];
  const float* gn1_b  = (const float*)d_in[10];
  const float* gn1_ms = (const float*)d_in[11];
  const float* gn2_w  = (const float*)d_in[12];
  const float* gn2_b  = (const float*)d_in[13];
  const float* gn2_ms = (const float*)d_in[14];
  const float* fc1_W  = (const float*)d_in[15];
  const float* fc1_b  = (const float*)d_in[16];
  const float* fc2_W  = (const float*)d_in[17];
  const float* fc2_b  = (const float*)d_in[18];
  const float* cls_W  = (const float*)d_in[19];
  const float* cls_b  = (const float*)d_in[20];
  float* logits = (float*)d_out;

  const int N = in_sizes[0] / FDIM;
  const int E = in_sizes[1] / 2;
  const int M = in_sizes[2] / FDIM;  // == 2048 (hist/scan/fill assume it)
  const int* row = eidx;
  const int* col = eidx + E;
  const size_t NS = (size_t)N * FDIM;
  const size_t MS = (size_t)M * FDIM;

  char* base = (char*)d_ws;
  auto alloc = [&](size_t bytes) { char* r = base; base += (bytes + 255) & ~(size_t)255; return r; };

  unsigned short* xhi = (unsigned short*)alloc(NS * 2);   // x-hi
  unsigned short* xh1 = (unsigned short*)alloc(NS * 2);   // hn1
  unsigned short* xh2 = (unsigned short*)alloc(NS * 2);   // hn2
  unsigned short* xl  = (unsigned short*)alloc(NS * 2);   // conv GEMM output, bf16
  unsigned short* hb  = (unsigned short*)alloc(NS * 2);   // pre-norm h, bf16
  unsigned short* ef  = (unsigned short*)alloc(MS * 2);
  unsigned short* w1th = (unsigned short*)alloc(FDIM * FDIM * 2);
  unsigned short* w2th = (unsigned short*)alloc(FDIM * FDIM * 2);
  unsigned short* f1th = (unsigned short*)alloc(FDIM * HIDDIM * 2);
  unsigned short* f1tl = (unsigned short*)alloc(FDIM * HIDDIM * 2);
  unsigned short* f2th = (unsigned short*)alloc(FDIM * HIDDIM * 2);
  unsigned short* f2tl = (unsigned short*)alloc(FDIM * HIDDIM * 2);
  float* wv1 = (float*)alloc(FDIM * 4);
  float* wv2 = (float*)alloc(FDIM * 4);
  float* ea1 = (float*)alloc((size_t)M * 4);
  float* ea2 = (float*)alloc((size_t)M * 4);
  float* arj = (float*)alloc((size_t)E * 4);
  int* off_r = (int*)alloc((size_t)(N + 1) * 4);
  int* off_c = (int*)alloc((size_t)(M + 1) * 4);
  int* gcur  = (int*)alloc((size_t)M * 4);
  int* rj    = (int*)alloc((size_t)E * 4);
  int* cj    = (int*)alloc((size_t)E * 4);
  int* prj   = (int*)alloc((size_t)E * 4);
  int* btot  = (int*)alloc(512 * 4);

  // ---- single contiguous zeroed region ----
  char* zstart = base;
  int* cnt_r = (int*)alloc((size_t)(2 * N + M) * 4);  // cnt_r | cur_r | cnt_c
  int* cur_r = cnt_r + N;
  int* cnt_c = cur_r + N;
  float* xa1 = (float*)alloc((size_t)N * 4);
  float* xa2 = (float*)alloc((size_t)N * 4);
  float* gsum1 = (float*)alloc(FDIM * 4);
  float* gsq1  = (float*)alloc(FDIM * 4);
  float* gsum2 = (float*)alloc(FDIM * 4);
  float* gsq2  = (float*)alloc(FDIM * 4);
  size_t zlen = (size_t)(base - zstart);
  hipMemsetAsync(zstart, 0, zlen, stream);
  hipMemsetAsync(logits, 0, (size_t)N * 2 * sizeof(float), stream);

  int nchunk = (E + HB - 1) / HB;
  int nbR = (N + SCH - 1) / SCH;
  k_hist2<<<HB, 256, 0, stream>>>(row, col, cnt_r, cnt_c, E, nchunk);
  k_scan_part<<<nbR, 256, 0, stream>>>(cnt_r, off_r, btot, N);
  k_scan_midcol<<<2, 256, 0, stream>>>(btot, nbR, cnt_c, off_c, gcur);
  k_scan_add<<<nbR, 256, 0, stream>>>(off_r, btot, N, nbR);
  k_fill3<<<HB, 256, 0, stream>>>(row, col, gcur, off_r, cur_r, prj, rj, cj, E, nchunk);

  k_hi<<<(int)((NS / 4 + 255) / 256), 256, 0, stream>>>(x, xhi, (int)(NS / 4));
  k_prep_w_hi2<<<dim3(FDIM / 16, FDIM / 16, 2), 256, 0, stream>>>(W1, w1th, W2, w2th, FDIM, FDIM);
  k_prep_w2<<<dim3(HIDDIM / 16, FDIM / 16, 2), 256, 0, stream>>>(fc1_W, f1th, f1tl, fc2_W, f2th, f2tl, FDIM, HIDDIM);
  k_wv2<<<dim3(FDIM / 4, 2), 256, 0, stream>>>(W1, att1 + FDIM, W2, att2 + FDIM, wv1, wv2);
  k_ea2<<<(M + 3) / 4, 256, 0, stream>>>(eattr, wv1, wv2, ea1, ea2, M);

  int gN128 = (N + 127) / 128;
  int nPpad4 = ((gN128 + 7) / 8) * 8 * 4;  // XCD-swizzled 1D GEMM grid
  int gPC = ((M + 3) / 4) * 8;             // prop_col: 2*M half-split blocks
  int napply_grid = (int)((NS / 2 + 255) / 256);
  float invn = 1.0f / (float)N;

  // ---- conv1 ----
  gemm_conv<<<nPpad4, 256, 0, stream>>>(xhi, w1th, xl, att1, xa1, N, FDIM, FDIM, gN128);
  k_prop_col_f<<<gPC, 256, 0, stream>>>(xl, xa1, ea1, rj, prj, off_c, arj, ef, M);
  k_prop_row<<<N, 256, 0, stream>>>(ef, arj, cj, off_r, b1, hb);
  k_stats<<<256, 256, 0, stream>>>(hb, gsum1, gsq1, N);
  k_napply<<<napply_grid, 256, 0, stream>>>(hb, gsum1, gsq1, gn1_ms, gn1_w, gn1_b, xh1, invn, (int)(NS / 2));

  // ---- conv2 ----
  gemm_conv<<<nPpad4, 256, 0, stream>>>(xh1, w2th, xl, att2, xa2, N, FDIM, FDIM, gN128);
  k_prop_col_f<<<gPC, 256, 0, stream>>>(xl, xa2, ea2, rj, prj, off_c, arj, ef, M);
  k_prop_row<<<N, 256, 0, stream>>>(ef, arj, cj, off_r, b2, hb);
  k_stats<<<256, 256, 0, stream>>>(hb, gsum2, gsq2, N);
  k_napply<<<napply_grid, 256, 0, stream>>>(hb, gsum2, gsq2, gn2_ms, gn2_w, gn2_b, xh2, invn, (int)(NS / 2));

  // ---- fc1 + fc2 + classifier, fused ----
  gemm_fc_cls<<<nPpad4, 256, 0, stream>>>(xh1, f1th, f1tl, fc1_b,
                                          xh2, f2th, f2tl, fc2_b,
                                          cls_W, cls_b, logits, N, FDIM, gN128);
}